// Round 7
// baseline (441.393 us; speedup 1.0000x reference)
//
#include <hip/hip_runtime.h>

#define N_USERS  100000
#define EMBED    128
#define NPHASE   8
#define BUCKETW  12500              // N_USERS / NPHASE
#define RPB      100                // dst rows per block in phased spmm
#define NBLK     1000               // N_USERS / RPB

typedef __attribute__((ext_vector_type(8))) short bf16x8;
typedef __attribute__((ext_vector_type(4))) float f32x4;
typedef __attribute__((ext_vector_type(4))) uint  u32x4;

// ---------------------------------------------------------------- row pointers
__global__ __launch_bounds__(256) void rowptr_kernel(const int* __restrict__ rows,
                                                     int* __restrict__ row_ptr,
                                                     int n_rows, int n_edges) {
  int r = blockIdx.x * blockDim.x + threadIdx.x;
  if (r > n_rows) return;
  int lo = 0, hi = n_edges;
  while (lo < hi) {
    int mid = (lo + hi) >> 1;
    if (rows[mid] < r) lo = mid + 1; else hi = mid;
  }
  row_ptr[r] = lo;
}

// ---------------------------------------------------------------- bucket edges
// Reorder each row's edges by source-column range (8 ranges of 12500).
// rp2[9*r + p] = start of range-p edges of row r in cols2/vals2; rp2[9*r+8]=end.
// One thread per row; 8 passes over the row's (L1-resident) edge list.
__global__ __launch_bounds__(256) void bucket_kernel(const int* __restrict__ row_ptr,
                                                     const int* __restrict__ cols,
                                                     const float* __restrict__ vals,
                                                     int* __restrict__ rp2,
                                                     int* __restrict__ cols2,
                                                     float* __restrict__ vals2) {
  int r = blockIdx.x * blockDim.x + threadIdx.x;
  if (r >= N_USERS) return;
  const int s = row_ptr[r], e = row_ptr[r + 1];
  int w = s;
  #pragma unroll
  for (int p = 0; p < NPHASE; ++p) {
    rp2[9 * r + p] = w;
    for (int i = s; i < e; ++i) {
      int c = cols[i];
      if (c / BUCKETW == p) { cols2[w] = c; vals2[w] = vals[i]; ++w; }
    }
  }
  rp2[9 * r + 8] = e;
}

// ---------------------------------------------------------------- W -> Wt bf16
__global__ __launch_bounds__(256) void wconv_kernel(const float* __restrict__ W0,
                                                    const float* __restrict__ W1,
                                                    uint* __restrict__ Wt0,
                                                    uint* __restrict__ Wt1) {
  const float* W  = blockIdx.x ? W1 : W0;
  uint*        Wt = blockIdx.x ? Wt1 : Wt0;
  for (int idx = threadIdx.x; idx < 128 * 64; idx += 256) {
    int n = idx >> 6;
    int kp = idx & 63;
    float a = W[(2 * kp) * 128 + n];
    float b = W[(2 * kp + 1) * 128 + n];
    uint o;
    asm("v_cvt_pk_bf16_f32 %0, %1, %2" : "=v"(o) : "v"(a), "v"(b));
    Wt[n * 64 + kp] = o;
  }
}

// ---------------------------------------------------------------- MFMA GEMM (R4 shape)
__global__ __launch_bounds__(256) void gemm_kernel(const float* __restrict__ X,
                                                   const ushort* __restrict__ Wt,
                                                   ushort* __restrict__ Y,
                                                   float* __restrict__ Xcopy) {
  const int tid  = threadIdx.x;
  const int wave = tid >> 6;
  const int lane = tid & 63;
  const int l15  = lane & 15;
  const int lg   = lane >> 4;
  const int m    = blockIdx.x * 64 + wave * 16 + l15;
  const int mc   = m < N_USERS ? m : N_USERS - 1;
  const bool act = m < N_USERS;
  const float* xrow = X + (size_t)mc * EMBED;

  f32x4 acc[8];
  #pragma unroll
  for (int t = 0; t < 8; ++t) acc[t] = (f32x4){0.f, 0.f, 0.f, 0.f};

  #pragma unroll
  for (int s = 0; s < 4; ++s) {
    const int k0 = s * 32 + lg * 8;
    float4 xa = *(const float4*)(xrow + k0);
    float4 xb = *(const float4*)(xrow + k0 + 4);
    if (Xcopy && act) {
      *(float4*)(Xcopy + (size_t)m * EMBED + k0)     = xa;
      *(float4*)(Xcopy + (size_t)m * EMBED + k0 + 4) = xb;
    }
    union { bf16x8 v; uint u[4]; } bfr;
    asm("v_cvt_pk_bf16_f32 %0, %1, %2" : "=v"(bfr.u[0]) : "v"(xa.x), "v"(xa.y));
    asm("v_cvt_pk_bf16_f32 %0, %1, %2" : "=v"(bfr.u[1]) : "v"(xa.z), "v"(xa.w));
    asm("v_cvt_pk_bf16_f32 %0, %1, %2" : "=v"(bfr.u[2]) : "v"(xb.x), "v"(xb.y));
    asm("v_cvt_pk_bf16_f32 %0, %1, %2" : "=v"(bfr.u[3]) : "v"(xb.z), "v"(xb.w));
    #pragma unroll
    for (int nt = 0; nt < 8; ++nt) {
      union { bf16x8 v; uint4 u; } afr;
      afr.u = *(const uint4*)(Wt + (size_t)(nt * 16 + l15) * 128 + k0);
      acc[nt] = __builtin_amdgcn_mfma_f32_16x16x32_bf16(afr.v, bfr.v, acc[nt], 0, 0, 0);
    }
  }

  if (act) {
    ushort* yrow = Y + (size_t)m * EMBED;
    #pragma unroll
    for (int nt = 0; nt < 8; ++nt) {
      uint2 o;
      asm("v_cvt_pk_bf16_f32 %0, %1, %2" : "=v"(o.x) : "v"(acc[nt][0]), "v"(acc[nt][1]));
      asm("v_cvt_pk_bf16_f32 %0, %1, %2" : "=v"(o.y) : "v"(acc[nt][2]), "v"(acc[nt][3]));
      *(uint2*)(yrow + nt * 16 + lg * 4) = o;
    }
  }
}

// ---------------------------------------------------------------- phased SpMM
// OUT[r] = X[r] + sum_e vals[e] * bf16(XT[cols[e]]), edges bucketed by col range.
// 1000 co-resident blocks sweep the 8 col-range phases in near-lockstep, so
// each 3.2 MB xt window is L2-resident while being gathered from.
// Block: 16 groups x 16 lanes; group g owns rows base+g+16*i (6-7 rows),
// accumulators live in registers across all phases.
__device__ __forceinline__ void fma8(float* acc, u32x4 g, float v) {
  acc[0] = fmaf(v, __uint_as_float(g[0] << 16),         acc[0]);
  acc[1] = fmaf(v, __uint_as_float(g[0] & 0xffff0000u), acc[1]);
  acc[2] = fmaf(v, __uint_as_float(g[1] << 16),         acc[2]);
  acc[3] = fmaf(v, __uint_as_float(g[1] & 0xffff0000u), acc[3]);
  acc[4] = fmaf(v, __uint_as_float(g[2] << 16),         acc[4]);
  acc[5] = fmaf(v, __uint_as_float(g[2] & 0xffff0000u), acc[5]);
  acc[6] = fmaf(v, __uint_as_float(g[3] << 16),         acc[6]);
  acc[7] = fmaf(v, __uint_as_float(g[3] & 0xffff0000u), acc[7]);
}

__global__ __launch_bounds__(256, 4) void spmm_phased(const ushort* __restrict__ XT,
                                                      const float* __restrict__ X,
                                                      const int* __restrict__ rp2,
                                                      const int* __restrict__ cols2,
                                                      const float* __restrict__ vals2,
                                                      float* __restrict__ OUT) {
  const int tid  = threadIdx.x;
  const int l    = tid & 15;               // 16B (8 cols) of a row per lane
  const int g    = tid >> 4;               // group 0..15
  const int base = blockIdx.x * RPB;
  const u32x4* XT4 = (const u32x4*)XT;

  float acc[7][8];
  #pragma unroll
  for (int i = 0; i < 7; ++i)
    #pragma unroll
    for (int j = 0; j < 8; ++j) acc[i][j] = 0.f;

  for (int p = 0; p < NPHASE; ++p) {
    #pragma unroll
    for (int i = 0; i < 7; ++i) {
      if (g + 16 * i < RPB) {
        const int r = base + g + 16 * i;
        const int s = rp2[9 * r + p];
        const int e = rp2[9 * r + p + 1];
        int e2 = s;
        for (; e2 + 2 <= e; e2 += 2) {
          int   c0 = cols2[e2],   c1 = cols2[e2 + 1];
          float v0 = vals2[e2],   v1 = vals2[e2 + 1];
          u32x4 g0 = XT4[(size_t)c0 * 16 + l];
          u32x4 g1 = XT4[(size_t)c1 * 16 + l];
          fma8(acc[i], g0, v0);
          fma8(acc[i], g1, v1);
        }
        if (e2 < e) {
          u32x4 g0 = XT4[(size_t)cols2[e2] * 16 + l];
          fma8(acc[i], g0, vals2[e2]);
        }
      }
    }
  }

  // epilogue: residual add + store
  #pragma unroll
  for (int i = 0; i < 7; ++i) {
    if (g + 16 * i < RPB) {
      const int r = base + g + 16 * i;
      const float* xr = X + (size_t)r * EMBED + l * 8;
      float4 r0 = *(const float4*)xr;
      float4 r1 = *(const float4*)(xr + 4);
      float4 o0 = {acc[i][0] + r0.x, acc[i][1] + r0.y,
                   acc[i][2] + r0.z, acc[i][3] + r0.w};
      float4 o1 = {acc[i][4] + r1.x, acc[i][5] + r1.y,
                   acc[i][6] + r1.z, acc[i][7] + r1.w};
      float* orow = OUT + (size_t)r * EMBED + l * 8;
      *(float4*)orow       = o0;
      *(float4*)(orow + 4) = o1;
    }
  }
}

// ---------------------------------------------------------------- launch
extern "C" void kernel_launch(void* const* d_in, const int* in_sizes, int n_in,
                              void* d_out, int out_size, void* d_ws, size_t ws_size,
                              hipStream_t stream) {
  const float* user_embeds = (const float*)d_in[0];
  const int*   s_rows      = (const int*)d_in[1];
  const int*   s_cols      = (const int*)d_in[2];
  const float* s_values    = (const float*)d_in[3];
  const float* W0          = (const float*)d_in[4];
  const float* W1          = (const float*)d_in[5];
  float* out = (float*)d_out;

  const int n_edges = in_sizes[1];
  const size_t layer = (size_t)N_USERS * EMBED;

  char* ws = (char*)d_ws;
  ushort* xt      = (ushort*)ws;  ws += layer * sizeof(ushort);            // 25.6 MB
  ushort* Wt0     = (ushort*)ws;  ws += 128 * 128 * sizeof(ushort);
  ushort* Wt1     = (ushort*)ws;  ws += 128 * 128 * sizeof(ushort);
  int*    row_ptr = (int*)ws;     ws += (N_USERS + 1) * sizeof(int) + 12;
  int*    rp2     = (int*)ws;     ws += (size_t)9 * N_USERS * sizeof(int); // 3.6 MB
  int*    cols2   = (int*)ws;     ws += (size_t)n_edges * sizeof(int);     // 6.4 MB
  float*  vals2   = (float*)ws;                                            // 6.4 MB

  rowptr_kernel<<<(N_USERS + 1 + 255) / 256, 256, 0, stream>>>(
      s_rows, row_ptr, N_USERS, n_edges);
  wconv_kernel<<<2, 256, 0, stream>>>(W0, W1, (uint*)Wt0, (uint*)Wt1);
  bucket_kernel<<<(N_USERS + 255) / 256, 256, 0, stream>>>(
      row_ptr, s_cols, s_values, rp2, cols2, vals2);

  const ushort* Wtl[2] = {Wt0, Wt1};
  for (int l = 0; l < 2; ++l) {
    // Layer 0 reads the ORIGINAL input (d_out is zeroed by the harness);
    // gemm0 streams user_embeds -> out[0].
    const float* Xl = (l == 0) ? user_embeds : (out + l * layer);
    gemm_kernel<<<(N_USERS + 63) / 64, 256, 0, stream>>>(
        Xl, Wtl[l], xt, l == 0 ? out : nullptr);
    spmm_phased<<<NBLK, 256, 0, stream>>>(
        xt, Xl, rp2, cols2, vals2, out + (l + 1) * layer);
  }
}

// Round 8
// 317.492 us; speedup vs baseline: 1.3903x; 1.3903x over previous
//
#include <hip/hip_runtime.h>

#define N_USERS  100000
#define EMBED    128
#define NPHASE   8
#define BUCKETW  12500              // N_USERS / NPHASE

typedef __attribute__((ext_vector_type(8))) short bf16x8;
typedef __attribute__((ext_vector_type(4))) float f32x4;
typedef __attribute__((ext_vector_type(4))) uint  u32x4;

// ---------------------------------------------------------------- row pointers
__global__ __launch_bounds__(256) void rowptr_kernel(const int* __restrict__ rows,
                                                     int* __restrict__ row_ptr,
                                                     int n_rows, int n_edges) {
  int r = blockIdx.x * blockDim.x + threadIdx.x;
  if (r > n_rows) return;
  int lo = 0, hi = n_edges;
  while (lo < hi) {
    int mid = (lo + hi) >> 1;
    if (rows[mid] < r) lo = mid + 1; else hi = mid;
  }
  row_ptr[r] = lo;
}

// ---------------------------------------------------------------- bucket edges
// Reorder each row's edges into ascending column-range order (8 ranges).
// Co-resident spmm blocks then sweep the xt address space roughly in lockstep,
// keeping the active gather window L2-resident (R7 evidence: FETCH 409->198MB).
__global__ __launch_bounds__(256) void bucket_kernel(const int* __restrict__ row_ptr,
                                                     const int* __restrict__ cols,
                                                     const float* __restrict__ vals,
                                                     int* __restrict__ cols2,
                                                     float* __restrict__ vals2) {
  int r = blockIdx.x * blockDim.x + threadIdx.x;
  if (r >= N_USERS) return;
  const int s = row_ptr[r], e = row_ptr[r + 1];
  int w = s;
  #pragma unroll
  for (int p = 0; p < NPHASE; ++p) {
    for (int i = s; i < e; ++i) {
      int c = cols[i];
      if (c / BUCKETW == p) { cols2[w] = c; vals2[w] = vals[i]; ++w; }
    }
  }
}

// ---------------------------------------------------------------- W -> Wt bf16
__global__ __launch_bounds__(256) void wconv_kernel(const float* __restrict__ W0,
                                                    const float* __restrict__ W1,
                                                    uint* __restrict__ Wt0,
                                                    uint* __restrict__ Wt1) {
  const float* W  = blockIdx.x ? W1 : W0;
  uint*        Wt = blockIdx.x ? Wt1 : Wt0;
  for (int idx = threadIdx.x; idx < 128 * 64; idx += 256) {
    int n = idx >> 6;
    int kp = idx & 63;
    float a = W[(2 * kp) * 128 + n];
    float b = W[(2 * kp + 1) * 128 + n];
    uint o;
    asm("v_cvt_pk_bf16_f32 %0, %1, %2" : "=v"(o) : "v"(a), "v"(b));
    Wt[n * 64 + kp] = o;
  }
}

// ---------------------------------------------------------------- MFMA GEMM (R4 shape)
__global__ __launch_bounds__(256) void gemm_kernel(const float* __restrict__ X,
                                                   const ushort* __restrict__ Wt,
                                                   ushort* __restrict__ Y,
                                                   float* __restrict__ Xcopy) {
  const int tid  = threadIdx.x;
  const int wave = tid >> 6;
  const int lane = tid & 63;
  const int l15  = lane & 15;
  const int lg   = lane >> 4;
  const int m    = blockIdx.x * 64 + wave * 16 + l15;
  const int mc   = m < N_USERS ? m : N_USERS - 1;
  const bool act = m < N_USERS;
  const float* xrow = X + (size_t)mc * EMBED;

  f32x4 acc[8];
  #pragma unroll
  for (int t = 0; t < 8; ++t) acc[t] = (f32x4){0.f, 0.f, 0.f, 0.f};

  #pragma unroll
  for (int s = 0; s < 4; ++s) {
    const int k0 = s * 32 + lg * 8;
    float4 xa = *(const float4*)(xrow + k0);
    float4 xb = *(const float4*)(xrow + k0 + 4);
    if (Xcopy && act) {
      *(float4*)(Xcopy + (size_t)m * EMBED + k0)     = xa;
      *(float4*)(Xcopy + (size_t)m * EMBED + k0 + 4) = xb;
    }
    union { bf16x8 v; uint u[4]; } bfr;
    asm("v_cvt_pk_bf16_f32 %0, %1, %2" : "=v"(bfr.u[0]) : "v"(xa.x), "v"(xa.y));
    asm("v_cvt_pk_bf16_f32 %0, %1, %2" : "=v"(bfr.u[1]) : "v"(xa.z), "v"(xa.w));
    asm("v_cvt_pk_bf16_f32 %0, %1, %2" : "=v"(bfr.u[2]) : "v"(xb.x), "v"(xb.y));
    asm("v_cvt_pk_bf16_f32 %0, %1, %2" : "=v"(bfr.u[3]) : "v"(xb.z), "v"(xb.w));
    #pragma unroll
    for (int nt = 0; nt < 8; ++nt) {
      union { bf16x8 v; uint4 u; } afr;
      afr.u = *(const uint4*)(Wt + (size_t)(nt * 16 + l15) * 128 + k0);
      acc[nt] = __builtin_amdgcn_mfma_f32_16x16x32_bf16(afr.v, bfr.v, acc[nt], 0, 0, 0);
    }
  }

  if (act) {
    ushort* yrow = Y + (size_t)m * EMBED;
    #pragma unroll
    for (int nt = 0; nt < 8; ++nt) {
      uint2 o;
      asm("v_cvt_pk_bf16_f32 %0, %1, %2" : "=v"(o.x) : "v"(acc[nt][0]), "v"(acc[nt][1]));
      asm("v_cvt_pk_bf16_f32 %0, %1, %2" : "=v"(o.y) : "v"(acc[nt][2]), "v"(acc[nt][3]));
      *(uint2*)(yrow + nt * 16 + lg * 4) = o;
    }
  }
}

// ---------------------------------------------------------------- SpMM + residual
// R4 structure (full occupancy + 4-deep MLP), edges pre-sorted by col range.
__device__ __forceinline__ void fma8(float* acc, u32x4 g, float v) {
  acc[0] = fmaf(v, __uint_as_float(g[0] << 16),         acc[0]);
  acc[1] = fmaf(v, __uint_as_float(g[0] & 0xffff0000u), acc[1]);
  acc[2] = fmaf(v, __uint_as_float(g[1] << 16),         acc[2]);
  acc[3] = fmaf(v, __uint_as_float(g[1] & 0xffff0000u), acc[3]);
  acc[4] = fmaf(v, __uint_as_float(g[2] << 16),         acc[4]);
  acc[5] = fmaf(v, __uint_as_float(g[2] & 0xffff0000u), acc[5]);
  acc[6] = fmaf(v, __uint_as_float(g[3] << 16),         acc[6]);
  acc[7] = fmaf(v, __uint_as_float(g[3] & 0xffff0000u), acc[7]);
}

__global__ __launch_bounds__(256) void spmm_kernel(const ushort* __restrict__ XT,
                                                   const float* __restrict__ X,
                                                   const int* __restrict__ row_ptr,
                                                   const int* __restrict__ cols,
                                                   const float* __restrict__ vals,
                                                   float* __restrict__ OUT) {
  const int tid = threadIdx.x;
  const int l   = tid & 15;        // 8 cols / 16B per lane
  const int rg  = tid >> 4;        // 16 rows per block
  const int row = blockIdx.x * 16 + rg;
  if (row >= N_USERS) return;
  const int start = row_ptr[row];
  const int end   = row_ptr[row + 1];
  const u32x4* XT4 = (const u32x4*)XT;   // row stride = 16

  float acc[8];
  {
    float4 r0 = *(const float4*)(X + (size_t)row * EMBED + l * 8);
    float4 r1 = *(const float4*)(X + (size_t)row * EMBED + l * 8 + 4);
    acc[0] = r0.x; acc[1] = r0.y; acc[2] = r0.z; acc[3] = r0.w;
    acc[4] = r1.x; acc[5] = r1.y; acc[6] = r1.z; acc[7] = r1.w;
  }

  int e = start;
  int e_pre = (start + 3) & ~3;    // peel to int4 alignment
  if (e_pre > end) e_pre = end;
  for (; e < e_pre; ++e) {
    u32x4 g = XT4[(size_t)cols[e] * 16 + l];
    fma8(acc, g, vals[e]);
  }
  for (; e + 4 <= end; e += 4) {
    int4   ca = *(const int4*)(cols + e);
    float4 va = *(const float4*)(vals + e);
    u32x4 g0 = XT4[(size_t)ca.x * 16 + l];
    u32x4 g1 = XT4[(size_t)ca.y * 16 + l];
    u32x4 g2 = XT4[(size_t)ca.z * 16 + l];
    u32x4 g3 = XT4[(size_t)ca.w * 16 + l];
    fma8(acc, g0, va.x); fma8(acc, g1, va.y);
    fma8(acc, g2, va.z); fma8(acc, g3, va.w);
  }
  for (; e < end; ++e) {
    u32x4 g = XT4[(size_t)cols[e] * 16 + l];
    fma8(acc, g, vals[e]);
  }

  float4 o0 = {acc[0], acc[1], acc[2], acc[3]};
  float4 o1 = {acc[4], acc[5], acc[6], acc[7]};
  *(float4*)(OUT + (size_t)row * EMBED + l * 8)     = o0;
  *(float4*)(OUT + (size_t)row * EMBED + l * 8 + 4) = o1;
}

// ---------------------------------------------------------------- launch
extern "C" void kernel_launch(void* const* d_in, const int* in_sizes, int n_in,
                              void* d_out, int out_size, void* d_ws, size_t ws_size,
                              hipStream_t stream) {
  const float* user_embeds = (const float*)d_in[0];
  const int*   s_rows      = (const int*)d_in[1];
  const int*   s_cols      = (const int*)d_in[2];
  const float* s_values    = (const float*)d_in[3];
  const float* W0          = (const float*)d_in[4];
  const float* W1          = (const float*)d_in[5];
  float* out = (float*)d_out;

  const int n_edges = in_sizes[1];
  const size_t layer = (size_t)N_USERS * EMBED;

  char* ws = (char*)d_ws;
  ushort* xt      = (ushort*)ws;  ws += layer * sizeof(ushort);            // 25.6 MB
  ushort* Wt0     = (ushort*)ws;  ws += 128 * 128 * sizeof(ushort);
  ushort* Wt1     = (ushort*)ws;  ws += 128 * 128 * sizeof(ushort);
  int*    row_ptr = (int*)ws;     ws += (N_USERS + 1) * sizeof(int) + 12;
  int*    cols2   = (int*)ws;     ws += (size_t)n_edges * sizeof(int);     // 6.4 MB
  float*  vals2   = (float*)ws;                                            // 6.4 MB

  rowptr_kernel<<<(N_USERS + 1 + 255) / 256, 256, 0, stream>>>(
      s_rows, row_ptr, N_USERS, n_edges);
  wconv_kernel<<<2, 256, 0, stream>>>(W0, W1, (uint*)Wt0, (uint*)Wt1);
  bucket_kernel<<<(N_USERS + 255) / 256, 256, 0, stream>>>(
      row_ptr, s_cols, s_values, cols2, vals2);

  const ushort* Wtl[2] = {Wt0, Wt1};
  for (int l = 0; l < 2; ++l) {
    // Layer 0 reads the ORIGINAL input (d_out is zeroed by the harness);
    // gemm0 streams user_embeds -> out[0].
    const float* Xl = (l == 0) ? user_embeds : (out + l * layer);
    gemm_kernel<<<(N_USERS + 63) / 64, 256, 0, stream>>>(
        Xl, Wtl[l], xt, l == 0 ? out : nullptr);
    spmm_kernel<<<(N_USERS + 15) / 16, 256, 0, stream>>>(
        xt, Xl, row_ptr, cols2, vals2, out + (l + 1) * layer);
  }
}